// Round 7
// baseline (139.429 us; speedup 1.0000x reference)
//
#include <hip/hip_runtime.h>

// ---------- types ----------
using bf16x8 = __attribute__((ext_vector_type(8))) __bf16;
using f32x4  = __attribute__((ext_vector_type(4))) float;
using f32x2  = __attribute__((ext_vector_type(2))) float;
using us8    = __attribute__((ext_vector_type(8))) unsigned short;

#define TWO_LOG2E 2.8853900817779268f
#define LOG2E 1.4426950408889634f

__device__ __forceinline__ unsigned short f2bf(float x) {
  unsigned int u = __float_as_uint(x);
  u = (u + 0x7fffu + ((u >> 16) & 1u)) >> 16;   // RNE
  return (unsigned short)u;
}
__device__ __forceinline__ float bf2f(unsigned short h) {
  return __uint_as_float(((unsigned int)h) << 16);
}
__device__ __forceinline__ f32x2 pk_fma(f32x2 a, f32x2 b, f32x2 c) {
  return __builtin_elementwise_fma(a, b, c);
}

// ---------- 1) tiled transpose+cast W/V + wv prologue ----------
__global__ __launch_bounds__(256) void tcast_kernel(
    const float* __restrict__ Wq, const float* __restrict__ Wk,
    const float* __restrict__ vals, const float* __restrict__ wv,
    unsigned short* __restrict__ wt_hi, unsigned short* __restrict__ wt_lo,
    unsigned short* __restrict__ vt_hi, unsigned short* __restrict__ vt_lo,
    float* __restrict__ wv2, float* __restrict__ Wsum) {
  if (blockIdx.x == 0) {
    int t = threadIdx.x;
    wv2[t] = -2.0f * wv[t];                       // folded weight for scores
    if (t < 64) {
      float s = wv[t] + wv[t + 64] + wv[t + 128] + wv[t + 192];
#pragma unroll
      for (int off = 1; off < 64; off <<= 1) s += __shfl_xor(s, off, 64);
      if (t == 0) Wsum[0] = s;
    }
  }
  __shared__ float tile[32][33];
  int m = blockIdx.x >> 6;                 // matrix 0..17
  int ts = blockIdx.x & 63;
  int R0 = (ts >> 3) << 5, C0 = (ts & 7) << 5;
  const float* src = (m == 0) ? Wq : (m == 1) ? Wk : (vals + ((m - 2) << 16));
  int r = threadIdx.x >> 3, c4 = (threadIdx.x & 7) << 2;
  float4 v = *(const float4*)(src + (R0 + r) * 256 + C0 + c4);
  tile[r][c4] = v.x; tile[r][c4 + 1] = v.y; tile[r][c4 + 2] = v.z; tile[r][c4 + 3] = v.w;
  __syncthreads();
  float o0 = tile[c4 + 0][r], o1 = tile[c4 + 1][r];
  float o2 = tile[c4 + 2][r], o3 = tile[c4 + 3][r];
  unsigned short h0 = f2bf(o0), h1 = f2bf(o1), h2 = f2bf(o2), h3 = f2bf(o3);
  int base = ((m < 2) ? (m << 16) : ((m - 2) << 16)) + (C0 + r) * 256 + R0 + c4;
  unsigned short* dh = (m < 2) ? wt_hi : vt_hi;
  unsigned short* dl = (m < 2) ? wt_lo : vt_lo;
  *(ushort4*)(dh + base) = make_ushort4(h0, h1, h2, h3);
  *(ushort4*)(dl + base) = make_ushort4(f2bf(o0 - bf2f(h0)), f2bf(o1 - bf2f(h1)),
                                        f2bf(o2 - bf2f(h2)), f2bf(o3 - bf2f(h3)));
}

// ---------- 2) projection GEMM + R = e^{2x} epilogue ----------
// q rows -> Rq[q][h]; key rows -> RkT[b][h][k] (pre-transposed for scores).
__global__ __launch_bounds__(256, 4) void proj_kernel(
    const float* __restrict__ q, const float* __restrict__ kk,
    const unsigned short* __restrict__ w_hi, const unsigned short* __restrict__ w_lo,
    const int* __restrict__ vlens, float* __restrict__ Rq, float* __restrict__ RkT) {
  int wave = threadIdx.x >> 6, lane = threadIdx.x & 63;
  int mt = (blockIdx.x << 1) + (wave & 1);   // m-tile 0..511
  int m0 = mt << 4;
  int g = mt >> 8;                           // 0: q rows / W_q, 1: k rows / W_k
  if (g) {                                   // key rows >= valid_len are never read
    int bb = (m0 >> 8) & 15;
    if ((m0 & 255) >= vlens[bb]) return;     // wave-uniform exit
  }
  int r = lane & 15, qd = lane >> 4;
  int row = m0 + r;
  const float* A = (g == 0) ? (q + row * 256) : (kk + (row - 4096) * 256);
  bf16x8 ah[8], al[8];
#pragma unroll
  for (int s = 0; s < 8; ++s) {
    const float* p = A + qd * 8 + s * 32;
    float4 f0 = *(const float4*)p;
    float4 f1 = *(const float4*)(p + 4);
    float fv[8] = {f0.x, f0.y, f0.z, f0.w, f1.x, f1.y, f1.z, f1.w};
#pragma unroll
    for (int j = 0; j < 8; ++j) {
      __bf16 h = (__bf16)fv[j];
      ah[s][j] = h;
      al[s][j] = (__bf16)(fv[j] - (float)h);
    }
  }
  int nbase = (blockIdx.y << 6) + ((wave >> 1) << 5);
#pragma unroll
  for (int tI = 0; tI < 2; ++tI) {
    int n0 = nbase + (tI << 4);
    int boff = (g << 16) + (n0 + r) * 256 + qd * 8;
    f32x4 acc = {0.f, 0.f, 0.f, 0.f};
#pragma unroll
    for (int s = 0; s < 8; ++s) {
      bf16x8 bh = *(const bf16x8*)(w_hi + boff + s * 32);
      bf16x8 bl = *(const bf16x8*)(w_lo + boff + s * 32);
      acc = __builtin_amdgcn_mfma_f32_16x16x32_bf16(ah[s], bh, acc, 0, 0, 0);
      acc = __builtin_amdgcn_mfma_f32_16x16x32_bf16(ah[s], bl, acc, 0, 0, 0);
      acc = __builtin_amdgcn_mfma_f32_16x16x32_bf16(al[s], bh, acc, 0, 0, 0);
    }
    f32x4 ex;
#pragma unroll
    for (int i = 0; i < 4; ++i) {
      float l = acc[i] * TWO_LOG2E;                 // log2(e^{2x})
      l = fminf(fmaxf(l, -27.f), 27.f);
      ex[i] = __builtin_amdgcn_exp2f(l);
    }
    if (g == 0) {
#pragma unroll
      for (int i = 0; i < 4; ++i)
        Rq[(m0 + qd * 4 + i) * 256 + n0 + r] = ex[i];
    } else {
      int b = (m0 >> 8) & 15;
      int kloc = (m0 & 255) + qd * 4;               // contiguous in i
      *(f32x4*)(RkT + (b << 16) + (n0 + r) * 256 + kloc) = ex;
    }
  }
}

// ---------- 3) scores[b][q][k] = Wsum + sum_h (-2 w_h)/(1 + Rq*Rk) ----------
// 32q x 32k tile; grid (b, k, q) with b fastest for CU load mixing;
// k-tiles past valid_len skipped. k staged straight from RkT (no transpose).
__global__ __launch_bounds__(256, 8) void scores_kernel(
    const float* __restrict__ Rq, const float* __restrict__ RkT,
    const float* __restrict__ wv2, const float* __restrict__ Wsum,
    const int* __restrict__ vlens, float* __restrict__ sc) {
  const int b = blockIdx.x;
  const int k0 = blockIdx.y << 5;
  const int vl = vlens[b];
  if (k0 >= vl) return;                 // masked columns: av forces them to 0
  __shared__ __align__(16) float rqs[32 * 76];   // [q][h]
  __shared__ __align__(16) float kT[64 * 34];    // [h][k]
  const int t = threadIdx.x;
  const int q0 = blockIdx.z << 5;
  const int qrow = (b << 8) + q0;
  const int tq = t >> 4, tk = t & 15;
  const int sr = t >> 3, shb = (t & 7) << 3;     // q staging
  const int hrow = t >> 2, kq = (t & 3) << 3;    // k staging: 64 rows x 8 cols/thread
  f32x2 a0 = {0.f, 0.f}, a1 = {0.f, 0.f};

  for (int hc = 0; hc < 4; ++hc) {
    if (hc) __syncthreads();
    const float* gq = Rq + (qrow + sr) * 256 + (hc << 6) + shb;
    *(float4*)(rqs + sr * 76 + shb)     = *(const float4*)gq;
    *(float4*)(rqs + sr * 76 + shb + 4) = *(const float4*)(gq + 4);
    const float* gk = RkT + (b << 16) + ((hc << 6) + hrow) * 256 + k0 + kq;
    *(float4*)(kT + hrow * 34 + kq)     = *(const float4*)gk;
    *(float4*)(kT + hrow * 34 + kq + 4) = *(const float4*)(gk + 4);
    __syncthreads();
#pragma unroll 2
    for (int h = 0; h < 64; h += 4) {
      f32x4 qa = *(const f32x4*)(rqs + tq * 76 + h);
      f32x4 qb = *(const f32x4*)(rqs + (tq + 16) * 76 + h);
      f32x4 wm = *(const f32x4*)(wv2 + (hc << 6) + h);
#pragma unroll
      for (int j = 0; j < 4; ++j) {
        f32x2 rk = *(const f32x2*)(kT + (h + j) * 34 + (tk << 1));
        f32x2 wj = (f32x2)(wm[j]);
        f32x2 d0 = pk_fma(rk, (f32x2)(qa[j]), (f32x2)(1.0f));
        f32x2 d1 = pk_fma(rk, (f32x2)(qb[j]), (f32x2)(1.0f));
        f32x2 r0, r1;
        r0.x = __uint_as_float(0x7EF311C3u - __float_as_uint(d0.x));
        r0.y = __uint_as_float(0x7EF311C3u - __float_as_uint(d0.y));
        r1.x = __uint_as_float(0x7EF311C3u - __float_as_uint(d1.x));
        r1.y = __uint_as_float(0x7EF311C3u - __float_as_uint(d1.y));
        r0 = r0 * pk_fma(-d0, r0, (f32x2)(2.0f));   // 1 Newton
        r1 = r1 * pk_fma(-d1, r1, (f32x2)(2.0f));
        a0 = pk_fma(r0, wj, a0);
        a1 = pk_fma(r1, wj, a1);
      }
    }
  }
  float ws = Wsum[0];
  a0 += (f32x2)(ws);
  a1 += (f32x2)(ws);
  *(f32x2*)(sc + ((qrow + tq) << 8) + k0 + (tk << 1)) = a0;
  *(f32x2*)(sc + ((qrow + tq + 16) << 8) + k0 + (tk << 1)) = a1;
}

// ---------- 4) fused masked-softmax + AV (K clamped to valid_len) ----------
__global__ __launch_bounds__(256) void av_fused_kernel(
    const float* __restrict__ sc, const int* __restrict__ vlens,
    const unsigned short* __restrict__ vhi, const unsigned short* __restrict__ vlo,
    float* __restrict__ out) {
  __shared__ __align__(16) unsigned short athi[16 * 264];
  const int wave = threadIdx.x >> 6, lane = threadIdx.x & 63;
  const int b = blockIdx.x;              // b fastest: mixes vl across CUs
  const int nh = blockIdx.y;             // n-half 0/1
  const int m0 = blockIdx.z << 4;
  const int vl = vlens[b];

  // --- softmax: wave handles rows wave*4 + (lane&3); lane holds 16 cols ---
  {
    int row = (wave << 2) + (lane & 3);
    int c0 = (lane >> 2) << 4;
    const float* srow = sc + ((b << 8) + m0 + row) * 256 + c0;
    float4 x0 = *(const float4*)(srow);
    float4 x1 = *(const float4*)(srow + 4);
    float4 x2 = *(const float4*)(srow + 8);
    float4 x3 = *(const float4*)(srow + 12);
    float p[16] = {x0.x, x0.y, x0.z, x0.w, x1.x, x1.y, x1.z, x1.w,
                   x2.x, x2.y, x2.z, x2.w, x3.x, x3.y, x3.z, x3.w};
#pragma unroll
    for (int i = 0; i < 16; ++i)
      if (c0 + i >= vl) p[i] = -1e6f;
    float mx = p[0];
#pragma unroll
    for (int i = 1; i < 16; ++i) mx = fmaxf(mx, p[i]);
#pragma unroll
    for (int off = 4; off <= 32; off <<= 1) mx = fmaxf(mx, __shfl_xor(mx, off, 64));
    float sm = 0.f;
#pragma unroll
    for (int i = 0; i < 16; ++i) {
      p[i] = __builtin_amdgcn_exp2f((p[i] - mx) * LOG2E);   // masked -> exactly 0
      sm += p[i];
    }
#pragma unroll
    for (int off = 4; off <= 32; off <<= 1) sm += __shfl_xor(sm, off, 64);
    float rs = __builtin_amdgcn_rcpf(sm);
    us8 vh[2];
#pragma unroll
    for (int i = 0; i < 16; ++i) vh[i >> 3][i & 7] = f2bf(p[i] * rs);
    *(us8*)(athi + row * 264 + c0)     = vh[0];
    *(us8*)(athi + row * 264 + c0 + 8) = vh[1];
  }
  __syncthreads();

  // --- AV: wave covers 2 n-tiles; K-loop clamped (attn cols >= vl are 0) ---
  const int r = lane & 15, qd = lane >> 4;
  const int smax = (vl + 31) >> 5;
#pragma unroll
  for (int tI = 0; tI < 2; ++tI) {
    int n0 = (nh << 7) + (wave << 5) + (tI << 4);
    int boff = (b << 16) + (n0 + r) * 256 + qd * 8;
    f32x4 acc = {0.f, 0.f, 0.f, 0.f};
    for (int s = 0; s < smax; ++s) {
      bf16x8 ah = *(const bf16x8*)(athi + r * 264 + qd * 8 + s * 32);
      bf16x8 bh = *(const bf16x8*)(vhi + boff + s * 32);
      bf16x8 bl = *(const bf16x8*)(vlo + boff + s * 32);
      acc = __builtin_amdgcn_mfma_f32_16x16x32_bf16(ah, bh, acc, 0, 0, 0);
      acc = __builtin_amdgcn_mfma_f32_16x16x32_bf16(ah, bl, acc, 0, 0, 0);
    }
#pragma unroll
    for (int i = 0; i < 4; ++i)
      out[(b << 16) + (m0 + qd * 4 + i) * 256 + n0 + r] = acc[i];
  }
}

extern "C" void kernel_launch(void* const* d_in, const int* in_sizes, int n_in,
                              void* d_out, int out_size, void* d_ws, size_t ws_size,
                              hipStream_t stream) {
  const float* queries = (const float*)d_in[0];
  const float* keys    = (const float*)d_in[1];
  const float* values  = (const float*)d_in[2];
  const int*   vlens   = (const int*)d_in[3];
  const float* Wq      = (const float*)d_in[4];
  const float* Wk      = (const float*)d_in[5];
  const float* wv      = (const float*)d_in[6];
  float* out = (float*)d_out;
  char* ws = (char*)d_ws;

  // workspace layout (bytes), total ~17.3 MB
  unsigned short* wt_hi = (unsigned short*)(ws + 0);          // 256 KB
  unsigned short* wt_lo = (unsigned short*)(ws + 262144);     // 256 KB
  unsigned short* vt_hi = (unsigned short*)(ws + 524288);     //   2 MB
  unsigned short* vt_lo = (unsigned short*)(ws + 2621440);    //   2 MB
  float*          Rq    = (float*)(ws + 4718592);             //   4 MB [q][h]
  float*          RkT   = (float*)(ws + 8912896);             //   4 MB [b][h][k]
  float*          sc    = (float*)(ws + 13107200);            //   4 MB
  float*          wv2   = (float*)(ws + 17301504);            //   1 KB
  float*          Wsum  = (float*)(ws + 17302528);            //   4 B

  tcast_kernel<<<1152, 256, 0, stream>>>(Wq, Wk, values, wv,
                                         wt_hi, wt_lo, vt_hi, vt_lo, wv2, Wsum);
  proj_kernel<<<dim3(256, 4), 256, 0, stream>>>(queries, keys, wt_hi, wt_lo,
                                                vlens, Rq, RkT);
  scores_kernel<<<dim3(16, 8, 8), 256, 0, stream>>>(Rq, RkT, wv2, Wsum, vlens, sc);
  av_fused_kernel<<<dim3(16, 2, 16), 256, 0, stream>>>(sc, vlens, vt_hi, vt_lo, out);
}

// Round 8
// 135.528 us; speedup vs baseline: 1.0288x; 1.0288x over previous
//
#include <hip/hip_runtime.h>

// ---------- types ----------
using bf16x8 = __attribute__((ext_vector_type(8))) __bf16;
using f32x4  = __attribute__((ext_vector_type(4))) float;
using f32x2  = __attribute__((ext_vector_type(2))) float;
using us8    = __attribute__((ext_vector_type(8))) unsigned short;

#define TWO_LOG2E 2.8853900817779268f
#define LOG2E 1.4426950408889634f

__device__ __forceinline__ unsigned short f2bf(float x) {
  unsigned int u = __float_as_uint(x);
  u = (u + 0x7fffu + ((u >> 16) & 1u)) >> 16;   // RNE
  return (unsigned short)u;
}
__device__ __forceinline__ float bf2f(unsigned short h) {
  return __uint_as_float(((unsigned int)h) << 16);
}
__device__ __forceinline__ f32x2 pk_fma(f32x2 a, f32x2 b, f32x2 c) {
  return __builtin_elementwise_fma(a, b, c);
}

// ---------- 1) tiled transpose+cast W/V + wv / work-list prologue ----------
__global__ __launch_bounds__(256) void tcast_kernel(
    const float* __restrict__ Wq, const float* __restrict__ Wk,
    const float* __restrict__ vals, const float* __restrict__ wv,
    const int* __restrict__ vlens,
    unsigned short* __restrict__ wt_hi, unsigned short* __restrict__ wt_lo,
    unsigned short* __restrict__ vt_hi, unsigned short* __restrict__ vt_lo,
    float* __restrict__ wv2, float* __restrict__ Wsum,
    int* __restrict__ ctr, int* __restrict__ cum) {
  if (blockIdx.x == 0) {
    int t = threadIdx.x;
    wv2[t] = -2.0f * wv[t];                       // folded weight for scores
    if (t < 64) {
      float s = wv[t] + wv[t + 64] + wv[t + 128] + wv[t + 192];
#pragma unroll
      for (int off = 1; off < 64; off <<= 1) s += __shfl_xor(s, off, 64);
      if (t == 0) Wsum[0] = s;
    }
    if (t == 0) {                                 // scores work list (valid tiles only)
      ctr[0] = 0;
      int c = 0;
      for (int b = 0; b < 16; ++b) {
        cum[b] = c;
        c += ((vlens[b] + 31) >> 5) << 3;         // ktiles(b) * 8 q-tiles
      }
      cum[16] = c;
    }
  }
  __shared__ float tile[32][33];
  int m = blockIdx.x >> 6;                 // matrix 0..17
  int ts = blockIdx.x & 63;
  int R0 = (ts >> 3) << 5, C0 = (ts & 7) << 5;
  const float* src = (m == 0) ? Wq : (m == 1) ? Wk : (vals + ((m - 2) << 16));
  int r = threadIdx.x >> 3, c4 = (threadIdx.x & 7) << 2;
  float4 v = *(const float4*)(src + (R0 + r) * 256 + C0 + c4);
  tile[r][c4] = v.x; tile[r][c4 + 1] = v.y; tile[r][c4 + 2] = v.z; tile[r][c4 + 3] = v.w;
  __syncthreads();
  float o0 = tile[c4 + 0][r], o1 = tile[c4 + 1][r];
  float o2 = tile[c4 + 2][r], o3 = tile[c4 + 3][r];
  unsigned short h0 = f2bf(o0), h1 = f2bf(o1), h2 = f2bf(o2), h3 = f2bf(o3);
  int base = ((m < 2) ? (m << 16) : ((m - 2) << 16)) + (C0 + r) * 256 + R0 + c4;
  unsigned short* dh = (m < 2) ? wt_hi : vt_hi;
  unsigned short* dl = (m < 2) ? wt_lo : vt_lo;
  *(ushort4*)(dh + base) = make_ushort4(h0, h1, h2, h3);
  *(ushort4*)(dl + base) = make_ushort4(f2bf(o0 - bf2f(h0)), f2bf(o1 - bf2f(h1)),
                                        f2bf(o2 - bf2f(h2)), f2bf(o3 - bf2f(h3)));
}

// ---------- 2) projection GEMM + R = e^{2x} epilogue ----------
// q rows -> Rq[q][h]; key rows -> RkT[b][h][k] (pre-transposed for scores).
__global__ __launch_bounds__(256, 4) void proj_kernel(
    const float* __restrict__ q, const float* __restrict__ kk,
    const unsigned short* __restrict__ w_hi, const unsigned short* __restrict__ w_lo,
    const int* __restrict__ vlens, float* __restrict__ Rq, float* __restrict__ RkT) {
  int wave = threadIdx.x >> 6, lane = threadIdx.x & 63;
  int mt = (blockIdx.x << 1) + (wave & 1);   // m-tile 0..511
  int m0 = mt << 4;
  int g = mt >> 8;                           // 0: q rows / W_q, 1: k rows / W_k
  if (g) {                                   // key rows >= valid_len are never read
    int bb = (m0 >> 8) & 15;
    if ((m0 & 255) >= vlens[bb]) return;     // wave-uniform exit
  }
  int r = lane & 15, qd = lane >> 4;
  int row = m0 + r;
  const float* A = (g == 0) ? (q + row * 256) : (kk + (row - 4096) * 256);
  bf16x8 ah[8], al[8];
#pragma unroll
  for (int s = 0; s < 8; ++s) {
    const float* p = A + qd * 8 + s * 32;
    float4 f0 = *(const float4*)p;
    float4 f1 = *(const float4*)(p + 4);
    float fv[8] = {f0.x, f0.y, f0.z, f0.w, f1.x, f1.y, f1.z, f1.w};
#pragma unroll
    for (int j = 0; j < 8; ++j) {
      __bf16 h = (__bf16)fv[j];
      ah[s][j] = h;
      al[s][j] = (__bf16)(fv[j] - (float)h);
    }
  }
  int nbase = (blockIdx.y << 6) + ((wave >> 1) << 5);
#pragma unroll
  for (int tI = 0; tI < 2; ++tI) {
    int n0 = nbase + (tI << 4);
    int boff = (g << 16) + (n0 + r) * 256 + qd * 8;
    f32x4 acc = {0.f, 0.f, 0.f, 0.f};
#pragma unroll
    for (int s = 0; s < 8; ++s) {
      bf16x8 bh = *(const bf16x8*)(w_hi + boff + s * 32);
      bf16x8 bl = *(const bf16x8*)(w_lo + boff + s * 32);
      acc = __builtin_amdgcn_mfma_f32_16x16x32_bf16(ah[s], bh, acc, 0, 0, 0);
      acc = __builtin_amdgcn_mfma_f32_16x16x32_bf16(ah[s], bl, acc, 0, 0, 0);
      acc = __builtin_amdgcn_mfma_f32_16x16x32_bf16(al[s], bh, acc, 0, 0, 0);
    }
    f32x4 ex;
#pragma unroll
    for (int i = 0; i < 4; ++i) {
      float l = acc[i] * TWO_LOG2E;                 // log2(e^{2x})
      l = fminf(fmaxf(l, -27.f), 27.f);
      ex[i] = __builtin_amdgcn_exp2f(l);
    }
    if (g == 0) {
#pragma unroll
      for (int i = 0; i < 4; ++i)
        Rq[(m0 + qd * 4 + i) * 256 + n0 + r] = ex[i];
    } else {
      int b = (m0 >> 8) & 15;
      int kloc = (m0 & 255) + qd * 4;               // contiguous in i
      *(f32x4*)(RkT + (b << 16) + (n0 + r) * 256 + kloc) = ex;
    }
  }
}

// ---------- 3) scores: persistent work-stealing over VALID 32q x 32k tiles ----------
// item w in [0, cum[16]): b = ub(cum, w); local = w-cum[b]; kt = local>>3; qt = local&7.
// 512 blocks (2/CU) pull from a global counter -> CUs drain the queue dynamically,
// converting the ~48% masked-tile savings into makespan (static skip couldn't).
__global__ __launch_bounds__(256, 8) void scores_kernel(
    const float* __restrict__ Rq, const float* __restrict__ RkT,
    const float* __restrict__ wv2, const float* __restrict__ Wsum,
    const int* __restrict__ cum, int* __restrict__ ctr,
    float* __restrict__ sc) {
  __shared__ __align__(16) float rqs[32 * 76];   // [q][h]
  __shared__ __align__(16) float kT[64 * 34];    // [h][k]
  __shared__ int s_item;
  const int t = threadIdx.x;
  const int tq = t >> 4, tk = t & 15;
  const int sr = t >> 3, shb = (t & 7) << 3;     // q staging
  const int hrow = t >> 2, kq = (t & 3) << 3;    // k staging
  const int total = cum[16];
  const float ws = Wsum[0];

  for (;;) {
    __syncthreads();                    // fences prev item's LDS reads + s_item
    if (t == 0) s_item = atomicAdd(ctr, 1);
    __syncthreads();
    const int w = s_item;
    if (w >= total) return;             // uniform exit
    int b = 0;
    while (cum[b + 1] <= w) ++b;        // <=16 uniform cached loads
    const int local = w - cum[b];
    const int k0 = (local >> 3) << 5;
    const int q0 = (local & 7) << 5;
    const int qrow = (b << 8) + q0;
    f32x2 a0 = {0.f, 0.f}, a1 = {0.f, 0.f};

    for (int hc = 0; hc < 4; ++hc) {
      if (hc) __syncthreads();
      const float* gq = Rq + (qrow + sr) * 256 + (hc << 6) + shb;
      *(float4*)(rqs + sr * 76 + shb)     = *(const float4*)gq;
      *(float4*)(rqs + sr * 76 + shb + 4) = *(const float4*)(gq + 4);
      const float* gk = RkT + (b << 16) + ((hc << 6) + hrow) * 256 + k0 + kq;
      *(float4*)(kT + hrow * 34 + kq)     = *(const float4*)gk;
      *(float4*)(kT + hrow * 34 + kq + 4) = *(const float4*)(gk + 4);
      __syncthreads();
#pragma unroll 2
      for (int h = 0; h < 64; h += 4) {
        f32x4 qa = *(const f32x4*)(rqs + tq * 76 + h);
        f32x4 qb = *(const f32x4*)(rqs + (tq + 16) * 76 + h);
        f32x4 wm = *(const f32x4*)(wv2 + (hc << 6) + h);
#pragma unroll
        for (int j = 0; j < 4; ++j) {
          f32x2 rk = *(const f32x2*)(kT + (h + j) * 34 + (tk << 1));
          f32x2 wj = (f32x2)(wm[j]);
          f32x2 d0 = pk_fma(rk, (f32x2)(qa[j]), (f32x2)(1.0f));
          f32x2 d1 = pk_fma(rk, (f32x2)(qb[j]), (f32x2)(1.0f));
          f32x2 r0, r1;
          r0.x = __uint_as_float(0x7EF311C3u - __float_as_uint(d0.x));
          r0.y = __uint_as_float(0x7EF311C3u - __float_as_uint(d0.y));
          r1.x = __uint_as_float(0x7EF311C3u - __float_as_uint(d1.x));
          r1.y = __uint_as_float(0x7EF311C3u - __float_as_uint(d1.y));
          r0 = r0 * pk_fma(-d0, r0, (f32x2)(2.0f));   // 1 Newton
          r1 = r1 * pk_fma(-d1, r1, (f32x2)(2.0f));
          a0 = pk_fma(r0, wj, a0);
          a1 = pk_fma(r1, wj, a1);
        }
      }
    }
    a0 += (f32x2)(ws);
    a1 += (f32x2)(ws);
    *(f32x2*)(sc + ((qrow + tq) << 8) + k0 + (tk << 1)) = a0;
    *(f32x2*)(sc + ((qrow + tq + 16) << 8) + k0 + (tk << 1)) = a1;
  }
}

// ---------- 4) fused masked-softmax + AV (K clamped to valid_len) ----------
__global__ __launch_bounds__(256) void av_fused_kernel(
    const float* __restrict__ sc, const int* __restrict__ vlens,
    const unsigned short* __restrict__ vhi, const unsigned short* __restrict__ vlo,
    float* __restrict__ out) {
  __shared__ __align__(16) unsigned short athi[16 * 264];
  const int wave = threadIdx.x >> 6, lane = threadIdx.x & 63;
  const int b = blockIdx.x;              // b fastest: mixes vl across CUs
  const int nh = blockIdx.y;             // n-half 0/1
  const int m0 = blockIdx.z << 4;
  const int vl = vlens[b];

  // --- softmax: wave handles rows wave*4 + (lane&3); lane holds 16 cols ---
  {
    int row = (wave << 2) + (lane & 3);
    int c0 = (lane >> 2) << 4;
    const float* srow = sc + ((b << 8) + m0 + row) * 256 + c0;
    float4 x0 = *(const float4*)(srow);
    float4 x1 = *(const float4*)(srow + 4);
    float4 x2 = *(const float4*)(srow + 8);
    float4 x3 = *(const float4*)(srow + 12);
    float p[16] = {x0.x, x0.y, x0.z, x0.w, x1.x, x1.y, x1.z, x1.w,
                   x2.x, x2.y, x2.z, x2.w, x3.x, x3.y, x3.z, x3.w};
#pragma unroll
    for (int i = 0; i < 16; ++i)
      if (c0 + i >= vl) p[i] = -1e6f;
    float mx = p[0];
#pragma unroll
    for (int i = 1; i < 16; ++i) mx = fmaxf(mx, p[i]);
#pragma unroll
    for (int off = 4; off <= 32; off <<= 1) mx = fmaxf(mx, __shfl_xor(mx, off, 64));
    float sm = 0.f;
#pragma unroll
    for (int i = 0; i < 16; ++i) {
      p[i] = __builtin_amdgcn_exp2f((p[i] - mx) * LOG2E);   // masked -> exactly 0
      sm += p[i];
    }
#pragma unroll
    for (int off = 4; off <= 32; off <<= 1) sm += __shfl_xor(sm, off, 64);
    float rs = __builtin_amdgcn_rcpf(sm);
    us8 vh[2];
#pragma unroll
    for (int i = 0; i < 16; ++i) vh[i >> 3][i & 7] = f2bf(p[i] * rs);
    *(us8*)(athi + row * 264 + c0)     = vh[0];
    *(us8*)(athi + row * 264 + c0 + 8) = vh[1];
  }
  __syncthreads();

  // --- AV: wave covers 2 n-tiles; K-loop clamped (attn cols >= vl are 0) ---
  const int r = lane & 15, qd = lane >> 4;
  const int smax = (vl + 31) >> 5;
#pragma unroll
  for (int tI = 0; tI < 2; ++tI) {
    int n0 = (nh << 7) + (wave << 5) + (tI << 4);
    int boff = (b << 16) + (n0 + r) * 256 + qd * 8;
    f32x4 acc = {0.f, 0.f, 0.f, 0.f};
    for (int s = 0; s < smax; ++s) {
      bf16x8 ah = *(const bf16x8*)(athi + r * 264 + qd * 8 + s * 32);
      bf16x8 bh = *(const bf16x8*)(vhi + boff + s * 32);
      bf16x8 bl = *(const bf16x8*)(vlo + boff + s * 32);
      acc = __builtin_amdgcn_mfma_f32_16x16x32_bf16(ah, bh, acc, 0, 0, 0);
      acc = __builtin_amdgcn_mfma_f32_16x16x32_bf16(ah, bl, acc, 0, 0, 0);
    }
#pragma unroll
    for (int i = 0; i < 4; ++i)
      out[(b << 16) + (m0 + qd * 4 + i) * 256 + n0 + r] = acc[i];
  }
}

extern "C" void kernel_launch(void* const* d_in, const int* in_sizes, int n_in,
                              void* d_out, int out_size, void* d_ws, size_t ws_size,
                              hipStream_t stream) {
  const float* queries = (const float*)d_in[0];
  const float* keys    = (const float*)d_in[1];
  const float* values  = (const float*)d_in[2];
  const int*   vlens   = (const int*)d_in[3];
  const float* Wq      = (const float*)d_in[4];
  const float* Wk      = (const float*)d_in[5];
  const float* wv      = (const float*)d_in[6];
  float* out = (float*)d_out;
  char* ws = (char*)d_ws;

  // workspace layout (bytes), total ~17.3 MB
  unsigned short* wt_hi = (unsigned short*)(ws + 0);          // 256 KB
  unsigned short* wt_lo = (unsigned short*)(ws + 262144);     // 256 KB
  unsigned short* vt_hi = (unsigned short*)(ws + 524288);     //   2 MB
  unsigned short* vt_lo = (unsigned short*)(ws + 2621440);    //   2 MB
  float*          Rq    = (float*)(ws + 4718592);             //   4 MB [q][h]
  float*          RkT   = (float*)(ws + 8912896);             //   4 MB [b][h][k]
  float*          sc    = (float*)(ws + 13107200);            //   4 MB
  float*          wv2   = (float*)(ws + 17301504);            //   1 KB
  float*          Wsum  = (float*)(ws + 17302528);            //   4 B
  int*            ctr   = (int*)(ws + 17302532);              //   4 B
  int*            cum   = (int*)(ws + 17302536);              //  68 B

  tcast_kernel<<<1152, 256, 0, stream>>>(Wq, Wk, values, wv, vlens,
                                         wt_hi, wt_lo, vt_hi, vt_lo, wv2, Wsum,
                                         ctr, cum);
  proj_kernel<<<dim3(256, 4), 256, 0, stream>>>(queries, keys, wt_hi, wt_lo,
                                                vlens, Rq, RkT);
  scores_kernel<<<512, 256, 0, stream>>>(Rq, RkT, wv2, Wsum, cum, ctr, sc);
  av_fused_kernel<<<dim3(16, 2, 16), 256, 0, stream>>>(sc, vlens, vt_hi, vt_lo, out);
}